// Round 6
// baseline (184.504 us; speedup 1.0000x reference)
//
#include <hip/hip_runtime.h>
#include <math.h>

// Problem constants (B=4, C=64, H=W=512, s=2 -> quadrant tiles of 256x256)
#define HH 512
#define WW 512
#define HW (HH * WW)          // 262144 = 2^18
#define CCH 64
#define BB 4
#define NBLOCKS (BB * HW / 4 / 256)   // 1024

typedef float    f4 __attribute__((ext_vector_type(4)));
typedef _Float16 h2 __attribute__((ext_vector_type(2)));
typedef _Float16 h4 __attribute__((ext_vector_type(4)));
typedef _Float16 h8 __attribute__((ext_vector_type(8)));

// ---------------------------------------------------------------------------
// Single fused kernel with a hand-rolled grid barrier.
// __launch_bounds__(256, 4): 4 blocks/CU min occupancy (VGPR <= 128), so all
// 1024 blocks are co-resident on 256 CUs -> barrier cannot deadlock. The
// counter is zeroed by hipMemsetAsync before each launch (deterministic).
//
// Phase 1: per-pixel channel reduction (4 px/thread, float4 loads).
//   Emits fp16 planes: l2 (2 B/px), interleaved (max,mean) (4 B/px).
// grid barrier (agent-scope atomics + fences -> cross-XCD visibility)
// Phase 2: both attention branches + sum, 4 consecutive output px/thread.
//
// local path index math (raw row-major reshape [B,4,256,256] -> [B,1,512,512]):
//   c = h>>7 ; hs = ((h&127)<<1)|(w>>8) ; ws = w&255
// tiles[b,i,y,x] = l2[b, (i>>1)*256 + y, (i&1)*256 + x], zero-padded in TILE
// space (guards on tile coords, NOT image coords).
// ---------------------------------------------------------------------------
__global__ __launch_bounds__(256, 4) void fused_k(const float* __restrict__ x,
                                                  _Float16* __restrict__ l2p,
                                                  h2* __restrict__ mmp,
                                                  unsigned* __restrict__ barrier_cnt,
                                                  const float* __restrict__ lw,
                                                  const float* __restrict__ lb,
                                                  const float* __restrict__ gw,
                                                  const float* __restrict__ gb,
                                                  float* __restrict__ out) {
    __shared__ float s_lw[144];   // [4,4,3,3]
    __shared__ float s_lb[4];
    __shared__ float s_gw[18];    // [1,2,3,3]
    __shared__ float s_gb;

    int t = threadIdx.x;
    if (t < 144) s_lw[t] = lw[t];
    if (t < 4)   s_lb[t] = lb[t];
    if (t < 18)  s_gw[t] = gw[t];
    if (t == 0)  s_gb = gb[0];

    int tid = blockIdx.x * 256 + t;                // 0 .. B*HW/4 - 1
    int b   = tid >> 16;                           // HW/4 = 65536
    int p4i = tid & 65535;

    // ---------------- Phase 1: channel reduction ----------------
    {
        const f4* xb = reinterpret_cast<const f4*>(x)
                     + (size_t)b * CCH * (HW / 4) + p4i;

        f4 ss = {0.f, 0.f, 0.f, 0.f};
        f4 sm = {0.f, 0.f, 0.f, 0.f};
        f4 mx = {-INFINITY, -INFINITY, -INFINITY, -INFINITY};

#pragma unroll 8
        for (int c = 0; c < CCH; ++c) {
            f4 v = xb[(size_t)c * (HW / 4)];
            ss += v * v;
            sm += v;
            mx.x = fmaxf(mx.x, v.x);
            mx.y = fmaxf(mx.y, v.y);
            mx.z = fmaxf(mx.z, v.z);
            mx.w = fmaxf(mx.w, v.w);
        }

        size_t o4 = (size_t)b * (HW / 4) + p4i;
        const float inv = 1.0f / 64.0f;
        h8 mm = { (_Float16)mx.x, (_Float16)(sm.x * inv),
                  (_Float16)mx.y, (_Float16)(sm.y * inv),
                  (_Float16)mx.z, (_Float16)(sm.z * inv),
                  (_Float16)mx.w, (_Float16)(sm.w * inv) };
        h4 l2v = { (_Float16)sqrtf(ss.x), (_Float16)sqrtf(ss.y),
                   (_Float16)sqrtf(ss.z), (_Float16)sqrtf(ss.w) };
        reinterpret_cast<h8*>(mmp)[o4] = mm;           // 16 B store
        reinterpret_cast<h4*>(l2p)[o4] = l2v;          // 8 B store
    }

    // ---------------- grid barrier (all 1024 blocks co-resident) ----------
    __syncthreads();
    if (t == 0) {
        // release: make phase-1 stores visible device-wide, then arrive
        __hip_atomic_fetch_add(barrier_cnt, 1u, __ATOMIC_ACQ_REL,
                               __HIP_MEMORY_SCOPE_AGENT);
        int spins = 0;
        while (__hip_atomic_load(barrier_cnt, __ATOMIC_ACQUIRE,
                                 __HIP_MEMORY_SCOPE_AGENT) < (unsigned)NBLOCKS) {
            __builtin_amdgcn_s_sleep(64);
            if (++spins > (1 << 18)) break;   // fail visibly, never hang
        }
    }
    __syncthreads();

    // ---------------- Phase 2: conv branches + sum ----------------
    int h  = p4i >> 7;
    int w0 = (p4i & 127) << 2;          // 0..508, multiple of 4

    const _Float16* l2b = l2p + ((size_t)b << 18);
    const h2*       mmb = mmp + ((size_t)b << 18);

    // global attention: 3x3 conv over (max, mean), relu, sigmoid
    float g0 = s_gb, g1 = s_gb, g2 = s_gb, g3 = s_gb;
#pragma unroll
    for (int dh = -1; dh <= 1; ++dh) {
        int hh = h + dh;
        if ((unsigned)hh >= (unsigned)HH) continue;
        const h2* row = mmb + hh * WW + w0;
        h8 v = *reinterpret_cast<const h8*>(row);   // px w0..w0+3, 16B aligned
        float m6[6], a6[6];
        if (w0 > 0) { h2 e = row[-1]; m6[0] = (float)e.x; a6[0] = (float)e.y; }
        else        { m6[0] = 0.f;    a6[0] = 0.f; }
        m6[1] = (float)v[0]; a6[1] = (float)v[1];
        m6[2] = (float)v[2]; a6[2] = (float)v[3];
        m6[3] = (float)v[4]; a6[3] = (float)v[5];
        m6[4] = (float)v[6]; a6[4] = (float)v[7];
        if (w0 < WW - 4) { h2 e = row[4]; m6[5] = (float)e.x; a6[5] = (float)e.y; }
        else             { m6[5] = 0.f;   a6[5] = 0.f; }
#pragma unroll
        for (int k = 0; k < 3; ++k) {
            float wmk = s_gw[(dh + 1) * 3 + k];
            float wak = s_gw[9 + (dh + 1) * 3 + k];
            g0 = fmaf(m6[0 + k], wmk, fmaf(a6[0 + k], wak, g0));
            g1 = fmaf(m6[1 + k], wmk, fmaf(a6[1 + k], wak, g1));
            g2 = fmaf(m6[2 + k], wmk, fmaf(a6[2 + k], wak, g2));
            g3 = fmaf(m6[3 + k], wmk, fmaf(a6[3 + k], wak, g3));
        }
    }

    // local attention: 3x3 conv (4 quadrant in-ch) in tile space
    int c   = h >> 7;
    int hs  = ((h & 127) << 1) | (w0 >> 8);
    int ws0 = w0 & 255;                // multiple of 4, 0..252

    float la0 = s_lb[c], la1 = la0, la2 = la0, la3 = la0;
#pragma unroll
    for (int i = 0; i < 4; ++i) {
        const _Float16* base = l2b + (i >> 1) * (256 * WW) + (i & 1) * 256;
        const float* wi = s_lw + c * 36 + i * 9;
#pragma unroll
        for (int dh = -1; dh <= 1; ++dh) {
            int y = hs + dh;
            if ((unsigned)y >= 256u) continue;
            const _Float16* row = base + y * WW + ws0;
            h4 v = *reinterpret_cast<const h4*>(row);   // 8B aligned
            float v6[6];
            v6[0] = (ws0 > 0)   ? (float)row[-1] : 0.f;
            v6[1] = (float)v[0]; v6[2] = (float)v[1];
            v6[3] = (float)v[2]; v6[4] = (float)v[3];
            v6[5] = (ws0 < 252) ? (float)row[4]  : 0.f;
#pragma unroll
            for (int k = 0; k < 3; ++k) {
                float wk = wi[(dh + 1) * 3 + k];
                la0 = fmaf(v6[0 + k], wk, la0);
                la1 = fmaf(v6[1 + k], wk, la1);
                la2 = fmaf(v6[2 + k], wk, la2);
                la3 = fmaf(v6[3 + k], wk, la3);
            }
        }
    }

    f4 o;
    o.x = 1.f / (1.f + __expf(-la0)) + 1.f / (1.f + __expf(-fmaxf(g0, 0.f)));
    o.y = 1.f / (1.f + __expf(-la1)) + 1.f / (1.f + __expf(-fmaxf(g1, 0.f)));
    o.z = 1.f / (1.f + __expf(-la2)) + 1.f / (1.f + __expf(-fmaxf(g2, 0.f)));
    o.w = 1.f / (1.f + __expf(-la3)) + 1.f / (1.f + __expf(-fmaxf(g3, 0.f)));
    __builtin_nontemporal_store(o, reinterpret_cast<f4*>(out) + tid);
}

extern "C" void kernel_launch(void* const* d_in, const int* in_sizes, int n_in,
                              void* d_out, int out_size, void* d_ws, size_t ws_size,
                              hipStream_t stream) {
    const float* x  = (const float*)d_in[0];   // [4,64,512,512]
    const float* lw = (const float*)d_in[1];   // [4,4,3,3]
    const float* lb = (const float*)d_in[2];   // [4]
    const float* gw = (const float*)d_in[3];   // [1,2,3,3]
    const float* gb = (const float*)d_in[4];   // [1]
    float* out = (float*)d_out;                // [4,1,512,512]

    // ws layout: mm plane (4 MiB) | l2 plane (2 MiB) | barrier counter
    h2*       mmp = (h2*)d_ws;
    _Float16* l2p = (_Float16*)((char*)d_ws + (size_t)BB * HW * sizeof(h2));
    unsigned* cnt = (unsigned*)((char*)d_ws + (size_t)BB * HW * 6);

    // zero the barrier counter every call (deterministic; capture-safe)
    hipMemsetAsync(cnt, 0, sizeof(unsigned), stream);

    fused_k<<<NBLOCKS, 256, 0, stream>>>(x, l2p, mmp, cnt,
                                         lw, lb, gw, gb, out);
}

// Round 7
// 58.235 us; speedup vs baseline: 3.1683x; 3.1683x over previous
//
#include <hip/hip_runtime.h>
#include <math.h>

// Problem constants (B=4, C=64, H=W=512, s=2 -> quadrant tiles of 256x256)
#define HH 512
#define WW 512
#define HW (HH * WW)          // 262144 = 2^18
#define CCH 64
#define BB 4

typedef float    f4 __attribute__((ext_vector_type(4)));
typedef _Float16 h2 __attribute__((ext_vector_type(2)));
typedef _Float16 h4 __attribute__((ext_vector_type(4)));
typedef _Float16 h8 __attribute__((ext_vector_type(8)));

// ---------------------------------------------------------------------------
// Kernel 1: per-pixel channel reduction, 4 px/thread (float4), 1024 blocks
// (16 waves/CU). ALL loads regular/cacheable: round-6 evidence shows the
// 256 MiB LLC serves ~half of x across graph replays, so NT loads (which
// bypass LLC hits) lose; deep unroll (16) keeps 16 KB of loads in flight
// per wave to tolerate the mixed LLC/HBM latency.
// Outputs fp16: l2 plane (2 B/px) + interleaved (max,mean) plane (4 B/px).
// ---------------------------------------------------------------------------
__global__ __launch_bounds__(256) void reduce_k(const float* __restrict__ x,
                                                _Float16* __restrict__ l2p,
                                                h2* __restrict__ mmp) {
    int tid = blockIdx.x * 256 + threadIdx.x;      // 0 .. B*HW/4 - 1
    int b  = tid >> 16;                            // HW/4 = 65536
    int p4 = tid & 65535;

    const f4* xb = reinterpret_cast<const f4*>(x)
                 + (size_t)b * CCH * (HW / 4) + p4;

    f4 ss = {0.f, 0.f, 0.f, 0.f};
    f4 sm = {0.f, 0.f, 0.f, 0.f};
    f4 mx = {-INFINITY, -INFINITY, -INFINITY, -INFINITY};

#pragma unroll 16
    for (int c = 0; c < CCH; ++c) {
        f4 v = xb[(size_t)c * (HW / 4)];
        ss += v * v;
        sm += v;
        mx.x = fmaxf(mx.x, v.x);
        mx.y = fmaxf(mx.y, v.y);
        mx.z = fmaxf(mx.z, v.z);
        mx.w = fmaxf(mx.w, v.w);
    }

    size_t o4 = (size_t)b * (HW / 4) + p4;
    const float inv = 1.0f / 64.0f;
    h8 mm = { (_Float16)mx.x, (_Float16)(sm.x * inv),
              (_Float16)mx.y, (_Float16)(sm.y * inv),
              (_Float16)mx.z, (_Float16)(sm.z * inv),
              (_Float16)mx.w, (_Float16)(sm.w * inv) };
    h4 l2v = { (_Float16)sqrtf(ss.x), (_Float16)sqrtf(ss.y),
               (_Float16)sqrtf(ss.z), (_Float16)sqrtf(ss.w) };
    reinterpret_cast<h8*>(mmp)[o4] = mm;           // 16 B store
    reinterpret_cast<h4*>(l2p)[o4] = l2v;          // 8 B store
}

// ---------------------------------------------------------------------------
// Kernel 2: both attention branches + sum, 4 consecutive output px/thread.
// Per conv row: one aligned vector load + 2 guarded edge loads, reused
// across the 4 outputs. fp16 inputs; fp32 accumulate. NT output store
// (out is never re-read; don't pollute caches).
//
// local path index math (raw row-major reshape [B,4,256,256] -> [B,1,512,512]):
//   c = h>>7 ; hs = ((h&127)<<1)|(w>>8) ; ws = w&255
// tiles[b,i,y,x] = l2[b, (i>>1)*256 + y, (i&1)*256 + x], zero-padded in TILE
// space (guards on tile coords, NOT image coords).
// ---------------------------------------------------------------------------
__global__ __launch_bounds__(256) void attn_k(const _Float16* __restrict__ l2p,
                                              const h2* __restrict__ mmp,
                                              const float* __restrict__ lw,
                                              const float* __restrict__ lb,
                                              const float* __restrict__ gw,
                                              const float* __restrict__ gb,
                                              float* __restrict__ out) {
    __shared__ float s_lw[144];   // [4,4,3,3]
    __shared__ float s_lb[4];
    __shared__ float s_gw[18];    // [1,2,3,3]
    __shared__ float s_gb;

    int t = threadIdx.x;
    if (t < 144) s_lw[t] = lw[t];
    if (t < 4)   s_lb[t] = lb[t];
    if (t < 18)  s_gw[t] = gw[t];
    if (t == 0)  s_gb = gb[0];
    __syncthreads();

    int idx4 = blockIdx.x * 256 + t;   // 0 .. B*HW/4 - 1
    int b  = idx4 >> 16;               // HW/4 = 65536
    int p4 = idx4 & 65535;
    int h  = p4 >> 7;
    int w0 = (p4 & 127) << 2;          // 0..508, multiple of 4

    const _Float16* l2b = l2p + ((size_t)b << 18);
    const h2*       mmb = mmp + ((size_t)b << 18);

    // ---- global attention: 3x3 conv over (max, mean), relu, sigmoid ----
    float g0 = s_gb, g1 = s_gb, g2 = s_gb, g3 = s_gb;
#pragma unroll
    for (int dh = -1; dh <= 1; ++dh) {
        int hh = h + dh;
        if ((unsigned)hh >= (unsigned)HH) continue;
        const h2* row = mmb + hh * WW + w0;
        h8 v = *reinterpret_cast<const h8*>(row);   // px w0..w0+3, 16B aligned
        float m6[6], a6[6];
        if (w0 > 0) { h2 e = row[-1]; m6[0] = (float)e.x; a6[0] = (float)e.y; }
        else        { m6[0] = 0.f;    a6[0] = 0.f; }
        m6[1] = (float)v[0]; a6[1] = (float)v[1];
        m6[2] = (float)v[2]; a6[2] = (float)v[3];
        m6[3] = (float)v[4]; a6[3] = (float)v[5];
        m6[4] = (float)v[6]; a6[4] = (float)v[7];
        if (w0 < WW - 4) { h2 e = row[4]; m6[5] = (float)e.x; a6[5] = (float)e.y; }
        else             { m6[5] = 0.f;   a6[5] = 0.f; }
#pragma unroll
        for (int k = 0; k < 3; ++k) {
            float wmk = s_gw[(dh + 1) * 3 + k];
            float wak = s_gw[9 + (dh + 1) * 3 + k];
            g0 = fmaf(m6[0 + k], wmk, fmaf(a6[0 + k], wak, g0));
            g1 = fmaf(m6[1 + k], wmk, fmaf(a6[1 + k], wak, g1));
            g2 = fmaf(m6[2 + k], wmk, fmaf(a6[2 + k], wak, g2));
            g3 = fmaf(m6[3 + k], wmk, fmaf(a6[3 + k], wak, g3));
        }
    }

    // ---- local attention: 3x3 conv (4 quadrant in-ch) in tile space ----
    int c   = h >> 7;
    int hs  = ((h & 127) << 1) | (w0 >> 8);
    int ws0 = w0 & 255;                // multiple of 4, 0..252

    float la0 = s_lb[c], la1 = la0, la2 = la0, la3 = la0;
#pragma unroll
    for (int i = 0; i < 4; ++i) {
        const _Float16* base = l2b + (i >> 1) * (256 * WW) + (i & 1) * 256;
        const float* wi = s_lw + c * 36 + i * 9;
#pragma unroll
        for (int dh = -1; dh <= 1; ++dh) {
            int y = hs + dh;
            if ((unsigned)y >= 256u) continue;
            const _Float16* row = base + y * WW + ws0;
            h4 v = *reinterpret_cast<const h4*>(row);   // 8B aligned
            float v6[6];
            v6[0] = (ws0 > 0)   ? (float)row[-1] : 0.f;
            v6[1] = (float)v[0]; v6[2] = (float)v[1];
            v6[3] = (float)v[2]; v6[4] = (float)v[3];
            v6[5] = (ws0 < 252) ? (float)row[4]  : 0.f;
#pragma unroll
            for (int k = 0; k < 3; ++k) {
                float wk = wi[(dh + 1) * 3 + k];
                la0 = fmaf(v6[0 + k], wk, la0);
                la1 = fmaf(v6[1 + k], wk, la1);
                la2 = fmaf(v6[2 + k], wk, la2);
                la3 = fmaf(v6[3 + k], wk, la3);
            }
        }
    }

    f4 o;
    o.x = 1.f / (1.f + __expf(-la0)) + 1.f / (1.f + __expf(-fmaxf(g0, 0.f)));
    o.y = 1.f / (1.f + __expf(-la1)) + 1.f / (1.f + __expf(-fmaxf(g1, 0.f)));
    o.z = 1.f / (1.f + __expf(-la2)) + 1.f / (1.f + __expf(-fmaxf(g2, 0.f)));
    o.w = 1.f / (1.f + __expf(-la3)) + 1.f / (1.f + __expf(-fmaxf(g3, 0.f)));
    __builtin_nontemporal_store(o, reinterpret_cast<f4*>(out) + idx4);
}

extern "C" void kernel_launch(void* const* d_in, const int* in_sizes, int n_in,
                              void* d_out, int out_size, void* d_ws, size_t ws_size,
                              hipStream_t stream) {
    const float* x  = (const float*)d_in[0];   // [4,64,512,512]
    const float* lw = (const float*)d_in[1];   // [4,4,3,3]
    const float* lb = (const float*)d_in[2];   // [4]
    const float* gw = (const float*)d_in[3];   // [1,2,3,3]
    const float* gb = (const float*)d_in[4];   // [1]
    float* out = (float*)d_out;                // [4,1,512,512]

    h2*       mmp = (h2*)d_ws;                           // 4 MiB (max,mean)/px
    _Float16* l2p = (_Float16*)((char*)d_ws + (size_t)BB * HW * sizeof(h2));

    int n1 = BB * HW / 4;                      // 262144 threads, 4 px each
    reduce_k<<<n1 / 256, 256, 0, stream>>>(x, l2p, mmp);

    int n2 = BB * HW / 4;
    attn_k<<<n2 / 256, 256, 0, stream>>>(l2p, mmp, lw, lb, gw, gb, out);
}